// Round 1
// baseline (47.080 us; speedup 1.0000x reference)
//
#include <hip/hip_runtime.h>

// Problem constants (fixed shapes from setup_inputs)
#define B 8
#define S 4096
#define H 1152
#define OUT 256
#define KP 4            // pooling window k = sqrt(S/OUT) = 4
#define CAP 32          // per-segment source-list capacity (actual = 16)

// ws layout (ints):
//   [0, B*OUT)                      counts
//   [B*OUT, B*OUT+B)                maxx (per-batch max of position_ids[...,0])
//   [B*OUT+B, B*OUT+B+B*OUT*CAP)   lists
#define WS_COUNTS 0
#define WS_MAXX   (B * OUT)
#define WS_LISTS  (B * OUT + B)

__global__ void init_ws_kernel(int* ws) {
    int i = blockIdx.x * blockDim.x + threadIdx.x;
    if (i < B * OUT) ws[WS_COUNTS + i] = 0;
    if (i < B) ws[WS_MAXX + i] = 0;
}

// Per-batch max of position_ids[...,0]; wave-reduce then one atomic per wave.
__global__ void maxx_kernel(const int* __restrict__ pos, int* ws) {
    int i = blockIdx.x * blockDim.x + threadIdx.x;  // over B*S
    int b = i / S;
    int px = pos[2 * i];
    // 64-lane wave reduce (all lanes in a wave share the same b: S % 64 == 0)
    for (int off = 32; off > 0; off >>= 1) {
        int o = __shfl_down(px, off, 64);
        px = px > o ? px : o;
    }
    if ((threadIdx.x & 63) == 0) atomicMax(&ws[WS_MAXX + b], px);
}

// Invert the segment mapping: for each (b,s) compute seg and append s.
__global__ void build_lists_kernel(const int* __restrict__ pos, int* ws) {
    int i = blockIdx.x * blockDim.x + threadIdx.x;  // over B*S
    int b = i / S;
    int s = i - b * S;
    int px = pos[2 * i];
    int py = pos[2 * i + 1];
    int mx = ws[WS_MAXX + b] + 1;          // = 64 for these inputs
    int seg = (px / KP) + (mx / KP) * (py / KP);
    int base = b * OUT + seg;
    int slot = atomicAdd(&ws[WS_COUNTS + base], 1);
    if (slot < CAP) ws[WS_LISTS + base * CAP + slot] = s;
}

// One block per (b, out_token): gather+sum 16 source rows, scale, bias, write.
__global__ __launch_bounds__(256) void pool_kernel(
    const float* __restrict__ x, const float* __restrict__ bias,
    const float* __restrict__ scale, const int* __restrict__ ws,
    float* __restrict__ out) {
    int bt = blockIdx.x;               // b * OUT + seg
    int b  = bt / OUT;
    int cnt = ws[WS_COUNTS + bt];
    if (cnt > CAP) cnt = CAP;

    __shared__ int src[CAP];
    if ((int)threadIdx.x < cnt) src[threadIdx.x] = ws[WS_LISTS + bt * CAP + threadIdx.x];
    __syncthreads();

    const float mul = sqrtf((float)H) * (1.0f / (KP * KP));
    const float* xb = x + (size_t)b * S * H;
    float* ob = out + (size_t)bt * H;

    for (int h4 = threadIdx.x; h4 < H / 4; h4 += 256) {
        float4 acc = make_float4(0.f, 0.f, 0.f, 0.f);
        #pragma unroll 4
        for (int i = 0; i < cnt; ++i) {
            const float4 v = *reinterpret_cast<const float4*>(xb + (size_t)src[i] * H + h4 * 4);
            acc.x += v.x; acc.y += v.y; acc.z += v.z; acc.w += v.w;
        }
        const float4 bs = *reinterpret_cast<const float4*>(bias + h4 * 4);
        const float4 sc = *reinterpret_cast<const float4*>(scale + h4 * 4);
        float4 r;
        r.x = (acc.x * mul - bs.x) * sc.x;
        r.y = (acc.y * mul - bs.y) * sc.y;
        r.z = (acc.z * mul - bs.z) * sc.z;
        r.w = (acc.w * mul - bs.w) * sc.w;
        *reinterpret_cast<float4*>(ob + h4 * 4) = r;
    }
}

extern "C" void kernel_launch(void* const* d_in, const int* in_sizes, int n_in,
                              void* d_out, int out_size, void* d_ws, size_t ws_size,
                              hipStream_t stream) {
    const float* x        = (const float*)d_in[0];
    const float* std_bias = (const float*)d_in[1];
    const float* std_scale= (const float*)d_in[2];
    const int*   pos      = (const int*)d_in[3];
    // d_in[4] = image_output_length (scalar on device) -> fixed 256 for this shape
    float* out = (float*)d_out;
    int* ws = (int*)d_ws;

    // 1. init counters/maxx
    init_ws_kernel<<<(B * OUT + 255) / 256, 256, 0, stream>>>(ws);
    // 2. per-batch max_x
    maxx_kernel<<<(B * S) / 256, 256, 0, stream>>>(pos, ws);
    // 3. inverted segment index
    build_lists_kernel<<<(B * S) / 256, 256, 0, stream>>>(pos, ws);
    // 4. gather + pool + affine
    pool_kernel<<<B * OUT, 256, 0, stream>>>(x, std_bias, std_scale, ws, out);
}

// Round 2
// 34.330 us; speedup vs baseline: 1.3714x; 1.3714x over previous
//
#include <hip/hip_runtime.h>

// Problem constants (fixed shapes from setup_inputs)
#define B 8
#define S 4096
#define H 1152
#define OUT 256
#define KP 4            // pooling window k = sqrt(S/OUT) = 4
#define CAP 16          // per-segment source rows (k*k = 16)
#define H4 (H / 4)      // 288 float4 per output row

// ws layout (ints):
//   [0, B*OUT)                    counts
//   [B*OUT, B*OUT + B*OUT*CAP)    lists
#define WS_COUNTS 0
#define WS_LISTS  (B * OUT)

// One block per batch: read pos once, find max_x, invert the segment map in
// LDS, dump counts+lists to ws.
__global__ __launch_bounds__(1024) void build_index_kernel(
    const int* __restrict__ pos, int* __restrict__ ws) {
    const int b = blockIdx.x;
    const int tid = threadIdx.x;

    __shared__ int s_max;
    __shared__ int s_cnt[OUT];
    __shared__ int s_lst[OUT][CAP];

    if (tid < OUT) s_cnt[tid] = 0;
    if (tid == 0) s_max = 0;

    // Load 4 positions per thread (int2 = 8B coalesced), local max.
    int px[4], py[4];
    int mymax = 0;
    #pragma unroll
    for (int j = 0; j < 4; ++j) {
        const int s = tid + j * 1024;
        const int2 p = reinterpret_cast<const int2*>(pos)[b * S + s];
        px[j] = p.x; py[j] = p.y;
        mymax = mymax > p.x ? mymax : p.x;
    }
    // Wave-reduce max, then one LDS atomic per wave.
    #pragma unroll
    for (int off = 32; off > 0; off >>= 1) {
        const int o = __shfl_down(mymax, off, 64);
        mymax = mymax > o ? mymax : o;
    }
    __syncthreads();               // s_max/s_cnt init visible
    if ((tid & 63) == 0) atomicMax(&s_max, mymax);
    __syncthreads();

    const int mxk = (s_max + 1) / KP;
    #pragma unroll
    for (int j = 0; j < 4; ++j) {
        const int s = tid + j * 1024;
        const int seg = px[j] / KP + mxk * (py[j] / KP);
        const int slot = atomicAdd(&s_cnt[seg], 1);
        if (slot < CAP) s_lst[seg][slot] = s;
    }
    __syncthreads();

    if (tid < OUT) ws[WS_COUNTS + b * OUT + tid] = s_cnt[tid];
    for (int i = tid; i < OUT * CAP; i += 1024) {
        const int seg = i / CAP, slot = i % CAP;
        ws[WS_LISTS + (b * OUT + seg) * CAP + slot] = s_lst[seg][slot];
    }
}

// One thread per output float4: gather 16 source rows, scale, bias, write.
__global__ __launch_bounds__(256) void pool_kernel(
    const float* __restrict__ x, const float* __restrict__ bias,
    const float* __restrict__ scale, const int* __restrict__ ws,
    float* __restrict__ out) {
    const int gid = blockIdx.x * 256 + threadIdx.x;   // over B*OUT*H4
    const int bt = gid / H4;                          // b*OUT + seg
    const int h4 = gid - bt * H4;
    const int b  = bt >> 8;                           // OUT = 256

    int cnt = ws[WS_COUNTS + bt];
    if (cnt > CAP) cnt = CAP;
    const int* lst = ws + WS_LISTS + bt * CAP;
    const float* xp = x + (size_t)b * S * H + (size_t)h4 * 4;

    float4 acc = make_float4(0.f, 0.f, 0.f, 0.f);
    if (cnt == CAP) {
        #pragma unroll
        for (int i = 0; i < CAP; ++i) {
            const float4 v = *reinterpret_cast<const float4*>(xp + (size_t)lst[i] * H);
            acc.x += v.x; acc.y += v.y; acc.z += v.z; acc.w += v.w;
        }
    } else {
        for (int i = 0; i < cnt; ++i) {
            const float4 v = *reinterpret_cast<const float4*>(xp + (size_t)lst[i] * H);
            acc.x += v.x; acc.y += v.y; acc.z += v.z; acc.w += v.w;
        }
    }

    const float mul = sqrtf((float)H) * (1.0f / (KP * KP));
    const float4 bs = *reinterpret_cast<const float4*>(bias + h4 * 4);
    const float4 sc = *reinterpret_cast<const float4*>(scale + h4 * 4);
    float4 r;
    r.x = (acc.x * mul - bs.x) * sc.x;
    r.y = (acc.y * mul - bs.y) * sc.y;
    r.z = (acc.z * mul - bs.z) * sc.z;
    r.w = (acc.w * mul - bs.w) * sc.w;
    *reinterpret_cast<float4*>(out + (size_t)gid * 4) = r;
}

extern "C" void kernel_launch(void* const* d_in, const int* in_sizes, int n_in,
                              void* d_out, int out_size, void* d_ws, size_t ws_size,
                              hipStream_t stream) {
    const float* x         = (const float*)d_in[0];
    const float* std_bias  = (const float*)d_in[1];
    const float* std_scale = (const float*)d_in[2];
    const int*   pos       = (const int*)d_in[3];
    // d_in[4] = image_output_length (scalar) -> 256 for this shape
    float* out = (float*)d_out;
    int* ws = (int*)d_ws;

    build_index_kernel<<<B, 1024, 0, stream>>>(pos, ws);
    pool_kernel<<<(B * OUT * H4) / 256, 256, 0, stream>>>(x, std_bias, std_scale, ws, out);
}

// Round 3
// 32.890 us; speedup vs baseline: 1.4315x; 1.0438x over previous
//
#include <hip/hip_runtime.h>

// Problem constants (fixed shapes from setup_inputs)
#define B 8
#define S 4096
#define H 1152
#define OUT 256
#define KP 4            // pooling window k = sqrt(S/OUT) = 4
#define CAP 16          // per-segment source rows (k*k = 16)
#define H4 (H / 4)      // 288 float4 per output row

// ws layout (ints):
//   [0, B*OUT)                    counts
//   [B*OUT, B*OUT + B*OUT*CAP)    lists
#define WS_COUNTS 0
#define WS_LISTS  (B * OUT)

// One block per batch: read pos once, find max_x, invert the segment map in
// LDS, dump counts+lists to ws.
__global__ __launch_bounds__(1024) void build_index_kernel(
    const int* __restrict__ pos, int* __restrict__ ws) {
    const int b = blockIdx.x;
    const int tid = threadIdx.x;

    __shared__ int s_max;
    __shared__ int s_cnt[OUT];
    __shared__ int s_lst[OUT][CAP];

    if (tid < OUT) s_cnt[tid] = 0;
    if (tid == 0) s_max = 0;

    // Load 4 positions per thread (int2 = 8B coalesced), local max.
    int px[4], py[4];
    int mymax = 0;
    #pragma unroll
    for (int j = 0; j < 4; ++j) {
        const int s = tid + j * 1024;
        const int2 p = reinterpret_cast<const int2*>(pos)[b * S + s];
        px[j] = p.x; py[j] = p.y;
        mymax = mymax > p.x ? mymax : p.x;
    }
    // Wave-reduce max, then one LDS atomic per wave.
    #pragma unroll
    for (int off = 32; off > 0; off >>= 1) {
        const int o = __shfl_down(mymax, off, 64);
        mymax = mymax > o ? mymax : o;
    }
    __syncthreads();               // s_max/s_cnt init visible
    if ((tid & 63) == 0) atomicMax(&s_max, mymax);
    __syncthreads();

    const int mxk = (s_max + 1) / KP;
    #pragma unroll
    for (int j = 0; j < 4; ++j) {
        const int s = tid + j * 1024;
        const int seg = px[j] / KP + mxk * (py[j] / KP);
        const int slot = atomicAdd(&s_cnt[seg], 1);
        if (slot < CAP) s_lst[seg][slot] = s;
    }
    __syncthreads();

    if (tid < OUT) ws[WS_COUNTS + b * OUT + tid] = s_cnt[tid];
    for (int i = tid; i < OUT * CAP; i += 1024) {
        const int seg = i / CAP, slot = i % CAP;
        ws[WS_LISTS + (b * OUT + seg) * CAP + slot] = s_lst[seg][slot];
    }
}

// One block = 2 output tokens = 576 threads, one float4 per thread.
// Lists staged in LDS once per block; zero tail, no token straddle.
__global__ __launch_bounds__(576) void pool_kernel(
    const float* __restrict__ x, const float* __restrict__ bias,
    const float* __restrict__ scale, const int* __restrict__ ws,
    float* __restrict__ out) {
    const int tp = blockIdx.x;          // token pair, over B*OUT/2
    const int tid = threadIdx.x;

    __shared__ int s_lst[2][CAP];
    __shared__ int s_cnt[2];

    if (tid < 2) {
        int c = ws[WS_COUNTS + tp * 2 + tid];
        s_cnt[tid] = c > CAP ? CAP : c;
    }
    if (tid >= 64 && tid < 64 + CAP)
        s_lst[0][tid - 64] = ws[WS_LISTS + (tp * 2) * CAP + (tid - 64)];
    else if (tid >= 128 && tid < 128 + CAP)
        s_lst[1][tid - 128] = ws[WS_LISTS + (tp * 2 + 1) * CAP + (tid - 128)];
    __syncthreads();

    const int k  = tid >= H4 ? 1 : 0;
    const int h4 = tid - k * H4;
    const int bt = tp * 2 + k;
    const int b  = bt >> 8;             // OUT = 256
    const int cnt = s_cnt[k];
    const float* xp = x + (size_t)b * S * H + (size_t)h4 * 4;

    float4 acc = make_float4(0.f, 0.f, 0.f, 0.f);
    if (cnt == CAP) {
        #pragma unroll
        for (int i = 0; i < CAP; ++i) {
            const float4 v = *reinterpret_cast<const float4*>(xp + (size_t)s_lst[k][i] * H);
            acc.x += v.x; acc.y += v.y; acc.z += v.z; acc.w += v.w;
        }
    } else {
        for (int i = 0; i < cnt; ++i) {
            const float4 v = *reinterpret_cast<const float4*>(xp + (size_t)s_lst[k][i] * H);
            acc.x += v.x; acc.y += v.y; acc.z += v.z; acc.w += v.w;
        }
    }

    const float mul = sqrtf((float)H) * (1.0f / (KP * KP));
    const float4 bs = *reinterpret_cast<const float4*>(bias + h4 * 4);
    const float4 sc = *reinterpret_cast<const float4*>(scale + h4 * 4);
    float4 r;
    r.x = (acc.x * mul - bs.x) * sc.x;
    r.y = (acc.y * mul - bs.y) * sc.y;
    r.z = (acc.z * mul - bs.z) * sc.z;
    r.w = (acc.w * mul - bs.w) * sc.w;
    *reinterpret_cast<float4*>(out + (size_t)bt * H + (size_t)h4 * 4) = r;
}

extern "C" void kernel_launch(void* const* d_in, const int* in_sizes, int n_in,
                              void* d_out, int out_size, void* d_ws, size_t ws_size,
                              hipStream_t stream) {
    const float* x         = (const float*)d_in[0];
    const float* std_bias  = (const float*)d_in[1];
    const float* std_scale = (const float*)d_in[2];
    const int*   pos       = (const int*)d_in[3];
    // d_in[4] = image_output_length (scalar) -> 256 for this shape
    float* out = (float*)d_out;
    int* ws = (int*)d_ws;

    build_index_kernel<<<B, 1024, 0, stream>>>(pos, ws);
    pool_kernel<<<B * OUT / 2, 576, 0, stream>>>(x, std_bias, std_scale, ws, out);
}

// Round 4
// 31.113 us; speedup vs baseline: 1.5132x; 1.0571x over previous
//
#include <hip/hip_runtime.h>

// Problem constants (fixed shapes from setup_inputs)
#define B 8
#define S 4096
#define H 1152
#define OUT 256
#define KP 4            // pooling window k = sqrt(S/OUT) = 4
#define CAP 16          // per-segment source rows (k*k = 16)
#define H4 (H / 4)      // 288 float4 per output row
#define NT 576          // threads per block = 2 tokens * H4
#define PPT 8           // ceil(S / NT) positions per thread

// Fully fused: one block = 2 output tokens. Each block redundantly builds the
// segment lists for its own 2 tokens by scanning its batch's position row
// (32 KB, L2-resident), then gathers + pools + affine-transforms.
__global__ __launch_bounds__(NT) void fused_pool_kernel(
    const float* __restrict__ x, const float* __restrict__ bias,
    const float* __restrict__ scale, const int* __restrict__ pos,
    float* __restrict__ out) {
    const int tp  = blockIdx.x;         // token pair, over B*OUT/2
    const int tid = threadIdx.x;
    const int b   = tp >> 7;            // 128 pairs per batch
    const int seg0 = (tp * 2) & 255;    // first token's segment within batch

    __shared__ int s_max;
    __shared__ int s_cnt[2];
    __shared__ int s_lst[2][CAP];

    if (tid == 0) s_max = 0;
    if (tid < 2) s_cnt[tid] = 0;

    // Pass 1: load this batch's positions (int2 coalesced), thread-local max.
    int px[PPT], py[PPT];
    int mymax = 0;
    #pragma unroll
    for (int j = 0; j < PPT; ++j) {
        const int s = tid + j * NT;
        if (s < S) {
            const int2 p = reinterpret_cast<const int2*>(pos)[b * S + s];
            px[j] = p.x; py[j] = p.y;
            mymax = mymax > p.x ? mymax : p.x;
        } else { px[j] = -1; py[j] = 0; }
    }
    #pragma unroll
    for (int off = 32; off > 0; off >>= 1) {
        const int o = __shfl_down(mymax, off, 64);
        mymax = mymax > o ? mymax : o;
    }
    __syncthreads();                    // s_max/s_cnt init visible
    if ((tid & 63) == 0) atomicMax(&s_max, mymax);
    __syncthreads();
    const int mxk = (s_max + 1) / KP;

    // Pass 2: segment-match for this block's two tokens -> LDS lists.
    #pragma unroll
    for (int j = 0; j < PPT; ++j) {
        if (px[j] >= 0) {
            const int seg = px[j] / KP + mxk * (py[j] / KP);
            const int k = seg - seg0;   // 0 or 1 if ours
            if (k == 0 || k == 1) {
                const int slot = atomicAdd(&s_cnt[k], 1);
                if (slot < CAP) s_lst[k][slot] = tid + j * NT;
            }
        }
    }
    __syncthreads();

    // Gather + pool + affine: one float4 per thread, zero tail.
    const int k  = tid >= H4 ? 1 : 0;
    const int h4 = tid - k * H4;
    const int bt = tp * 2 + k;
    int cnt = s_cnt[k];
    if (cnt > CAP) cnt = CAP;
    const float* xp = x + (size_t)b * S * H + (size_t)h4 * 4;

    float4 acc = make_float4(0.f, 0.f, 0.f, 0.f);
    if (cnt == CAP) {
        #pragma unroll
        for (int i = 0; i < CAP; ++i) {
            const float4 v = *reinterpret_cast<const float4*>(xp + (size_t)s_lst[k][i] * H);
            acc.x += v.x; acc.y += v.y; acc.z += v.z; acc.w += v.w;
        }
    } else {
        for (int i = 0; i < cnt; ++i) {
            const float4 v = *reinterpret_cast<const float4*>(xp + (size_t)s_lst[k][i] * H);
            acc.x += v.x; acc.y += v.y; acc.z += v.z; acc.w += v.w;
        }
    }

    const float mul = sqrtf((float)H) * (1.0f / (KP * KP));
    const float4 bs = *reinterpret_cast<const float4*>(bias + h4 * 4);
    const float4 sc = *reinterpret_cast<const float4*>(scale + h4 * 4);
    float4 r;
    r.x = (acc.x * mul - bs.x) * sc.x;
    r.y = (acc.y * mul - bs.y) * sc.y;
    r.z = (acc.z * mul - bs.z) * sc.z;
    r.w = (acc.w * mul - bs.w) * sc.w;
    *reinterpret_cast<float4*>(out + (size_t)bt * H + (size_t)h4 * 4) = r;
}

extern "C" void kernel_launch(void* const* d_in, const int* in_sizes, int n_in,
                              void* d_out, int out_size, void* d_ws, size_t ws_size,
                              hipStream_t stream) {
    const float* x         = (const float*)d_in[0];
    const float* std_bias  = (const float*)d_in[1];
    const float* std_scale = (const float*)d_in[2];
    const int*   pos       = (const int*)d_in[3];
    // d_in[4] = image_output_length (scalar) -> 256 for this shape
    float* out = (float*)d_out;

    fused_pool_kernel<<<B * OUT / 2, NT, 0, stream>>>(x, std_bias, std_scale, pos, out);
}

// Round 5
// 29.485 us; speedup vs baseline: 1.5967x; 1.0552x over previous
//
#include <hip/hip_runtime.h>

// Problem constants (fixed shapes from setup_inputs)
#define B 8
#define S 4096
#define H 1152
#define OUT 256
#define KP 4            // pooling window k = sqrt(S/OUT) = 4
#define CAP 16          // per-segment source rows (k*k = 16)
#define H4 (H / 4)      // 288 float4 per output row
#define NT 576          // threads per block = 2 tokens * H4
#define TPB 8           // tokens per block
#define NI4 (S / 2)     // int4 position-pair entries per batch

// Fully fused: one block = 8 output tokens. Each block scans its batch's
// position row once (32 KB, L2-resident), builds 8 segment lists in LDS,
// then runs 4 gather iterations (2 tokens each, one float4 per thread).
__global__ __launch_bounds__(NT) void fused_pool_kernel(
    const float* __restrict__ x, const float* __restrict__ bias,
    const float* __restrict__ scale, const int* __restrict__ pos,
    float* __restrict__ out) {
    const int blk = blockIdx.x;         // over B*OUT/TPB = 256
    const int tid = threadIdx.x;
    const int b   = blk >> 5;           // 32 blocks per batch
    const int seg_base = (blk * TPB) & 255;

    __shared__ int s_max;
    __shared__ int s_cnt[TPB];
    __shared__ int s_lst[TPB][CAP];

    if (tid == 0) s_max = 0;
    if (tid < TPB) s_cnt[tid] = 0;

    // Pass 1: load this batch's positions (int4 = 2 coords, coalesced).
    int px[8], py[8];
    int mymax = 0;
    #pragma unroll
    for (int j = 0; j < 4; ++j) {
        const int i4 = tid + j * NT;
        if (i4 < NI4) {
            const int4 p = reinterpret_cast<const int4*>(pos)[b * NI4 + i4];
            px[2 * j] = p.x;     py[2 * j] = p.y;
            px[2 * j + 1] = p.z; py[2 * j + 1] = p.w;
            mymax = mymax > p.x ? mymax : p.x;
            mymax = mymax > p.z ? mymax : p.z;
        } else {
            px[2 * j] = -1; py[2 * j] = 0;
            px[2 * j + 1] = -1; py[2 * j + 1] = 0;
        }
    }
    #pragma unroll
    for (int off = 32; off > 0; off >>= 1) {
        const int o = __shfl_down(mymax, off, 64);
        mymax = mymax > o ? mymax : o;
    }
    __syncthreads();                    // s_max/s_cnt init visible
    if ((tid & 63) == 0) atomicMax(&s_max, mymax);
    __syncthreads();
    const int mxk = (s_max + 1) / KP;

    // Pass 2: match positions against this block's 8 segments -> LDS lists.
    #pragma unroll
    for (int j = 0; j < 8; ++j) {
        if (px[j] >= 0) {
            const int seg = px[j] / KP + mxk * (py[j] / KP);
            const unsigned m = (unsigned)(seg - seg_base);
            if (m < (unsigned)TPB) {
                const int slot = atomicAdd(&s_cnt[m], 1);
                if (slot < CAP)
                    s_lst[m][slot] = 2 * (tid + (j >> 1) * NT) + (j & 1);
            }
        }
    }
    __syncthreads();

    // Gather + pool + affine: 4 iterations, one float4 per thread each.
    const int k  = tid >= H4 ? 1 : 0;
    const int h4 = tid - k * H4;
    const float* xp = x + (size_t)b * S * H + (size_t)h4 * 4;
    const float mul = sqrtf((float)H) * (1.0f / (KP * KP));
    const float4 bs = *reinterpret_cast<const float4*>(bias + h4 * 4);
    const float4 sc = *reinterpret_cast<const float4*>(scale + h4 * 4);

    for (int p = 0; p < TPB / 2; ++p) {
        const int m  = 2 * p + k;
        const int bt = blk * TPB + m;
        int cnt = s_cnt[m];
        if (cnt > CAP) cnt = CAP;

        float4 acc = make_float4(0.f, 0.f, 0.f, 0.f);
        if (cnt == CAP) {
            #pragma unroll
            for (int i = 0; i < CAP; ++i) {
                const float4 v = *reinterpret_cast<const float4*>(xp + (size_t)s_lst[m][i] * H);
                acc.x += v.x; acc.y += v.y; acc.z += v.z; acc.w += v.w;
            }
        } else {
            for (int i = 0; i < cnt; ++i) {
                const float4 v = *reinterpret_cast<const float4*>(xp + (size_t)s_lst[m][i] * H);
                acc.x += v.x; acc.y += v.y; acc.z += v.z; acc.w += v.w;
            }
        }
        float4 r;
        r.x = (acc.x * mul - bs.x) * sc.x;
        r.y = (acc.y * mul - bs.y) * sc.y;
        r.z = (acc.z * mul - bs.z) * sc.z;
        r.w = (acc.w * mul - bs.w) * sc.w;
        *reinterpret_cast<float4*>(out + (size_t)bt * H + (size_t)h4 * 4) = r;
    }
}

extern "C" void kernel_launch(void* const* d_in, const int* in_sizes, int n_in,
                              void* d_out, int out_size, void* d_ws, size_t ws_size,
                              hipStream_t stream) {
    const float* x         = (const float*)d_in[0];
    const float* std_bias  = (const float*)d_in[1];
    const float* std_scale = (const float*)d_in[2];
    const int*   pos       = (const int*)d_in[3];
    // d_in[4] = image_output_length (scalar) -> 256 for this shape
    float* out = (float*)d_out;

    fused_pool_kernel<<<B * OUT / TPB, NT, 0, stream>>>(x, std_bias, std_scale, pos, out);
}